// Round 7
// baseline (44.541 us; speedup 1.0000x reference)
//
#include <hip/hip_runtime.h>
#include <hip/hip_fp16.h>

#define MROWS 512
#define NCOLS 8192
#define NVALS 4096
#define BLOCK 512
#define NW 8
#define EPSF 1e-10f

typedef unsigned int u32;
typedef unsigned short u16;

// transposed layout: thread t owns logical e=8t..8t+7 at phys (i<<9)+t (conflict-free)
__device__ __forceinline__ int TP(int e) { return ((e & 7) << 9) | (e >> 3); }
__device__ __forceinline__ u16 f2h(float x) { return __half_as_ushort(__float2half_rn(x)); }
__device__ __forceinline__ float h2f(u16 h) { return __half2float(__ushort_as_half(h)); }

__global__ __launch_bounds__(BLOCK, 6) void listmle_row_kernel(
    const float* __restrict__ outputs,
    const float* __restrict__ runtime,
    const int*   __restrict__ idxs,
    float* __restrict__ row_out)
{
    // 16 + 16 + 8 + 8 = 48.2 KB -> 3 blocks/CU (24 waves/CU)
    __shared__ u32 A[NVALS];      // minidx -> bases -> cursors -> bucket ends
    __shared__ u32 KEY[NVALS];    // bucket counts (TP) -> compare keys (linear by pos)
    __shared__ u16 EXPH[NVALS];   // exp fp16 (linear by pos)
    __shared__ u16 T[NVALS];      // bucket totals -> exclusive sums (TP), fp16
    __shared__ float s_max[NW], s_ps[NW], s_fs[NW], s_lg[NW];
    __shared__ u32 s_cnt[NW];

    const int tid = threadIdx.x, lane = tid & 63, wave = tid >> 6;
    const int row = blockIdx.x;
    const float* rp = outputs + (size_t)row * NCOLS;
    const float* rr = runtime + (size_t)row * NCOLS;
    const int*   ri = idxs    + (size_t)row * NCOLS;

    // ---- P0: load 16 items/thread; column j(m) = (m>>2)*2048 + tid*4 + (m&3) ----
    u32 pidx[8]; u32 vkey[16]; float vpred[16];
    #pragma unroll
    for (int q = 0; q < 4; ++q) {
        const int b0 = (q << 11) + (tid << 2);
        const int4   i4 = *reinterpret_cast<const int4*>(ri + b0);
        const float4 r4 = *reinterpret_cast<const float4*>(rr + b0);
        const float4 p4 = *reinterpret_cast<const float4*>(rp + b0);
        pidx[q*2]   = ((u32)i4.x & 0xFFFFu) | ((u32)i4.y << 16);
        pidx[q*2+1] = ((u32)i4.z & 0xFFFFu) | ((u32)i4.w << 16);
        const float rv[4] = { r4.x, r4.y, r4.z, r4.w };
        #pragma unroll
        for (int r = 0; r < 4; ++r) {
            u32 u = (u32)(rv[r] * 16777216.0f);         // exact monotone 24-bit key
            vkey[q*4+r] = u > 0xFFFFFFu ? 0xFFFFFFu : u;
        }
        vpred[q*4+0]=p4.x; vpred[q*4+1]=p4.y; vpred[q*4+2]=p4.z; vpred[q*4+3]=p4.w;
    }
    #pragma unroll
    for (int i = 0; i < 8; ++i) { A[(i<<9)+tid] = 0xFFFFFFFFu; KEY[(i<<9)+tid] = 0u; }
    {
        u32* t32 = reinterpret_cast<u32*>(T);
        #pragma unroll
        for (int i = 0; i < 4; ++i) t32[(i<<9)+tid] = 0u;
    }
    __syncthreads();                                    // B1

    // ---- P1: dedup — first occurrence (min column) per value ----
    #pragma unroll
    for (int m = 0; m < 16; ++m) {
        const u32 v = (pidx[m>>1] >> ((m & 1) << 4)) & 0xFFFFu;
        const u32 j = ((m >> 2) << 11) + (tid << 2) + (m & 3);
        atomicMin(&A[v], j);
    }
    __syncthreads();                                    // B2

    // ---- P2: kept mask; bucket counts into KEY; max of all preds; sum of kept preds ----
    float lmax = -INFINITY, psum = 0.f;
    u32 kept = 0;
    #pragma unroll
    for (int m = 0; m < 16; ++m) {
        lmax = fmaxf(lmax, vpred[m]);
        const u32 v = (pidx[m>>1] >> ((m & 1) << 4)) & 0xFFFFu;
        const u32 j = ((m >> 2) << 11) + (tid << 2) + (m & 3);
        if (A[v] == j) {
            kept |= 1u << m;
            psum += vpred[m];
            atomicAdd(&KEY[TP((int)(vkey[m] >> 12))], 1u);
        }
    }
    #pragma unroll
    for (int off = 32; off > 0; off >>= 1) {
        lmax = fmaxf(lmax, __shfl_down(lmax, off));
        psum += __shfl_down(psum, off);
    }
    if (lane == 0) { s_max[wave] = lmax; s_ps[wave] = psum; }
    __syncthreads();                                    // B3 (minidx reads + counts done)

    float mx = s_max[0];
    #pragma unroll
    for (int w = 1; w < NW; ++w) mx = fmaxf(mx, s_max[w]);

    // ---- P3: exclusive scan of 4096 bucket counts (8/thread, TP layout) ----
    u32 c8[8], lsum = 0;
    #pragma unroll
    for (int i = 0; i < 8; ++i) { c8[i] = KEY[(i<<9)+tid]; lsum += c8[i]; }
    u32 xs = lsum;
    #pragma unroll
    for (int off = 1; off < 64; off <<= 1) { u32 y = __shfl_up(xs, off); if (lane >= off) xs += y; }
    if (lane == 63) s_cnt[wave] = xs;
    __syncthreads();                                    // B4

    u32 run = xs - lsum, K = 0;
    #pragma unroll
    for (int w = 0; w < NW; ++w) { const u32 t = s_cnt[w]; if (w < wave) run += t; K += t; }
    #pragma unroll
    for (int i = 0; i < 8; ++i) { const u32 c = c8[i]; A[(i<<9)+tid] = run; run += c; }
    __syncthreads();                                    // B5 (bases in A; KEY count slots dead)

    // ---- P5: scatter (cmpkey, fp16 exp) by atomic arrival; cursor IS the base array ----
    #pragma unroll
    for (int m = 0; m < 16; ++m) {
        if (kept & (1u << m)) {
            const u32 j = ((m >> 2) << 11) + (tid << 2) + (m & 3);
            const u32 k = vkey[m];
            const u32 pos = atomicAdd(&A[TP((int)(k >> 12))], 1u);
            KEY[pos]  = ((k & 0xFFFu) << 13) | j;       // unique: (low12, column)
            EXPH[pos] = f2h(__expf(vpred[m] - mx));
        }
    }
    __syncthreads();                                    // B6 (A[b] = end of bucket b)

    // ---- P6: within-bucket inclusive prefix (double accum = order-independent);
    //          max-key item writes fp16 bucket total into T ----
    float pf[16];
    #pragma unroll
    for (int m = 0; m < 16; ++m) {
        if (kept & (1u << m)) {
            const u32 j = ((m >> 2) << 11) + (tid << 2) + (m & 3);
            const u32 k = vkey[m];
            const int b = (int)(k >> 12);
            const u32 start = b ? A[TP(b - 1)] : 0u;
            const u32 end   = A[TP(b)];
            const u32 ck = ((k & 0xFFFu) << 13) | j;
            double dsm = 0.0;
            float eo = 0.f;
            u32 r = 0;
            for (u32 q = start; q < end; ++q) {
                const u32 k2 = KEY[q];
                if (k2 < ck) { dsm += (double)h2f(EXPH[q]); ++r; }
                else if (k2 == ck) eo = h2f(EXPH[q]);
            }
            const float pfm = (float)(dsm + (double)eo);
            pf[m] = pfm;
            if (r == end - start - 1u)                  // unique max-key item per bucket
                T[TP(b)] = f2h(pfm);                    // empty buckets keep 0.0
        }
    }
    __syncthreads();                                    // B7

    // ---- P7: exclusive f32 scan of 4096 fp16 bucket totals ----
    float f8[8], fsum = 0.f;
    #pragma unroll
    for (int i = 0; i < 8; ++i) { f8[i] = h2f(T[(i<<9)+tid]); fsum += f8[i]; }
    float xf = fsum;
    #pragma unroll
    for (int off = 1; off < 64; off <<= 1) { float y = __shfl_up(xf, off); if (lane >= off) xf += y; }
    if (lane == 63) s_fs[wave] = xf;
    __syncthreads();                                    // B8

    float frun = xf - fsum;
    #pragma unroll
    for (int w = 0; w < NW; ++w) if (w < wave) frun += s_fs[w];
    #pragma unroll
    for (int i = 0; i < 8; ++i) { const float c = f8[i]; T[(i<<9)+tid] = f2h(frun); frun += c; }
    __syncthreads();                                    // B9

    // ---- P9: logs: inclusive global prefix = S_excl[bucket] + pf ----
    float logacc = 0.f;
    #pragma unroll
    for (int m = 0; m < 16; ++m) {
        if (kept & (1u << m)) {
            const float S = h2f(T[TP((int)(vkey[m] >> 12))]);
            logacc += __logf(S + pf[m] + EPSF);
        }
    }
    #pragma unroll
    for (int off = 32; off > 0; off >>= 1) logacc += __shfl_down(logacc, off);
    if (lane == 0) s_lg[wave] = logacc;
    __syncthreads();                                    // B10

    if (tid == 0) {
        float lt = 0.f, pt = 0.f;
        #pragma unroll
        for (int w = 0; w < NW; ++w) { lt += s_lg[w]; pt += s_ps[w]; }
        row_out[row] = lt - pt + (float)K * mx;
    }
}

__global__ __launch_bounds__(256) void listmle_finalize(
    const float* __restrict__ row_out, float* __restrict__ out)
{
    __shared__ double red_d[4];
    const int tid = threadIdx.x;
    const int lane = tid & 63, wave = tid >> 6;
    double acc = 0.0;
    for (int r = tid; r < MROWS; r += 256) acc += (double)row_out[r];
    #pragma unroll
    for (int off = 32; off > 0; off >>= 1) acc += __shfl_down(acc, off);
    if (lane == 0) red_d[wave] = acc;
    __syncthreads();
    if (tid == 0) {
        double tot = 0.0;
        for (int w = 0; w < 4; ++w) tot += red_d[w];
        out[0] = (float)(tot / (double)MROWS);
    }
}

extern "C" void kernel_launch(void* const* d_in, const int* in_sizes, int n_in,
                              void* d_out, int out_size, void* d_ws, size_t ws_size,
                              hipStream_t stream) {
    const float* outputs = (const float*)d_in[0];
    const float* runtime = (const float*)d_in[1];
    const int*   idxs    = (const int*)d_in[2];
    float* out = (float*)d_out;
    float* ws  = (float*)d_ws;

    listmle_row_kernel<<<MROWS, BLOCK, 0, stream>>>(outputs, runtime, idxs, ws);
    listmle_finalize<<<1, 256, 0, stream>>>(ws, out);
}

// Round 8
// 39.341 us; speedup vs baseline: 1.1322x; 1.1322x over previous
//
#include <hip/hip_runtime.h>
#include <hip/hip_fp16.h>

#define MROWS 512
#define NCOLS 8192
#define NVALS 4096
#define BLOCK 1024
#define NW 16
#define EPSF 1e-10f

typedef unsigned int u32;
typedef unsigned short u16;

// transposed layout: thread t owns logical e=4t..4t+3 at phys (i<<10)+t (conflict-free)
__device__ __forceinline__ int TP(int e) { return ((e & 3) << 10) | (e >> 2); }
__device__ __forceinline__ u16 f2h(float x) { return __half_as_ushort(__float2half_rn(x)); }
__device__ __forceinline__ float h2f(u16 h) { return __half2float(__ushort_as_half(h)); }

__global__ __launch_bounds__(BLOCK, 4) void listmle_row_kernel(
    const float* __restrict__ outputs,
    const float* __restrict__ runtime,
    const int*   __restrict__ idxs,
    float* __restrict__ row_out)
{
    // 16 + 16 + 8 + 8 KB = 48.2 KB
    __shared__ u32 A[NVALS];      // minidx -> bucket bases -> cursors -> bucket ends
    __shared__ u32 KEY[NVALS];    // bucket counts (TP) -> compare keys (linear by pos)
    __shared__ u16 EXPH[NVALS];   // fp16 exp values (linear by pos)
    __shared__ u16 T[NVALS];      // fp16 bucket totals -> exclusive sums (TP)
    __shared__ float s_max[NW], s_ps[NW], s_fs[NW], s_lg[NW];
    __shared__ u32 s_cnt[NW];

    const int tid = threadIdx.x, lane = tid & 63, wave = tid >> 6;
    const int row = blockIdx.x;
    const float* rp = outputs + (size_t)row * NCOLS;
    const float* rr = runtime + (size_t)row * NCOLS;
    const int*   ri = idxs    + (size_t)row * NCOLS;

    // ---- P0: load 8 items/thread; column j(m) = (m>>2)*4096 + tid*4 + (m&3) ----
    u32 pidx[4]; u32 vkey[8]; float vpred[8];
    #pragma unroll
    for (int q = 0; q < 2; ++q) {
        const int b0 = (q << 12) + (tid << 2);
        const int4   i4 = *reinterpret_cast<const int4*>(ri + b0);
        const float4 r4 = *reinterpret_cast<const float4*>(rr + b0);
        const float4 p4 = *reinterpret_cast<const float4*>(rp + b0);
        pidx[q*2]   = ((u32)i4.x & 0xFFFFu) | ((u32)i4.y << 16);
        pidx[q*2+1] = ((u32)i4.z & 0xFFFFu) | ((u32)i4.w << 16);
        const float rv[4] = { r4.x, r4.y, r4.z, r4.w };
        #pragma unroll
        for (int r = 0; r < 4; ++r) {
            u32 u = (u32)(rv[r] * 16777216.0f);         // exact monotone 24-bit key
            vkey[q*4+r] = u > 0xFFFFFFu ? 0xFFFFFFu : u;
        }
        vpred[q*4+0]=p4.x; vpred[q*4+1]=p4.y; vpred[q*4+2]=p4.z; vpred[q*4+3]=p4.w;
    }
    #pragma unroll
    for (int i = 0; i < 4; ++i) { A[(i<<10)+tid] = 0xFFFFFFFFu; KEY[(i<<10)+tid] = 0u; }
    __syncthreads();                                    // B1

    // ---- P1: dedup — first occurrence (min column) per value ----
    #pragma unroll
    for (int m = 0; m < 8; ++m) {
        const u32 v = (pidx[m>>1] >> ((m & 1) << 4)) & 0xFFFFu;
        const u32 j = ((m >> 2) << 12) + (tid << 2) + (m & 3);
        atomicMin(&A[v], j);
    }
    __syncthreads();                                    // B2

    // ---- P2: kept mask; bucket counts into KEY; max of all preds; sum of kept preds ----
    float lmax = -INFINITY, psum = 0.f;
    u32 kept = 0;
    #pragma unroll
    for (int m = 0; m < 8; ++m) {
        lmax = fmaxf(lmax, vpred[m]);
        const u32 v = (pidx[m>>1] >> ((m & 1) << 4)) & 0xFFFFu;
        const u32 j = ((m >> 2) << 12) + (tid << 2) + (m & 3);
        if (A[v] == j) {
            kept |= 1u << m;
            psum += vpred[m];
            atomicAdd(&KEY[TP((int)(vkey[m] >> 12))], 1u);
        }
    }
    #pragma unroll
    for (int off = 32; off > 0; off >>= 1) {
        lmax = fmaxf(lmax, __shfl_down(lmax, off));
        psum += __shfl_down(psum, off);
    }
    if (lane == 0) { s_max[wave] = lmax; s_ps[wave] = psum; }
    __syncthreads();                                    // B3 (minidx reads + counts done)

    float mx = s_max[0];
    #pragma unroll
    for (int w = 1; w < NW; ++w) mx = fmaxf(mx, s_max[w]);

    // ---- P3: exclusive scan of 4096 bucket counts (4/thread, TP layout) ----
    u32 c4[4], lsum = 0;
    #pragma unroll
    for (int i = 0; i < 4; ++i) { c4[i] = KEY[(i<<10)+tid]; lsum += c4[i]; }
    u32 xs = lsum;
    #pragma unroll
    for (int off = 1; off < 64; off <<= 1) { u32 y = __shfl_up(xs, off); if (lane >= off) xs += y; }
    if (lane == 63) s_cnt[wave] = xs;
    __syncthreads();                                    // B4

    u32 run = xs - lsum, K = 0;
    #pragma unroll
    for (int w = 0; w < NW; ++w) { const u32 t = s_cnt[w]; if (w < wave) run += t; K += t; }
    #pragma unroll
    for (int i = 0; i < 4; ++i) { const u32 c = c4[i]; A[(i<<10)+tid] = run; run += c; }
    __syncthreads();                                    // B5 (bases in A)

    // ---- P5: scatter (cmpkey, fp16 exp) by atomic arrival; cursor IS the base array ----
    #pragma unroll
    for (int m = 0; m < 8; ++m) {
        if (kept & (1u << m)) {
            const u32 j = ((m >> 2) << 12) + (tid << 2) + (m & 3);
            const u32 k = vkey[m];
            const u32 pos = atomicAdd(&A[TP((int)(k >> 12))], 1u);
            KEY[pos]  = ((k & 0xFFFu) << 13) | j;       // unique: (low12, column<13b)
            EXPH[pos] = f2h(__expf(vpred[m] - mx));
        }
    }
    __syncthreads();                                    // B6 (A[b] = end of bucket b)

    // ---- P6: bucket totals by OWNER thread (4 contiguous buckets/thread);
    //          double accum over <=~20 fp16 values is exact -> order-independent ----
    {
        u32 start = (tid == 0) ? 0u : A[TP(4 * tid - 1)];
        #pragma unroll
        for (int i = 0; i < 4; ++i) {
            const u32 end = A[(i<<10)+tid];             // = A[TP(4*tid+i)]
            double ds = 0.0;
            for (u32 q = start; q < end; ++q) ds += (double)h2f(EXPH[q]);
            T[(i<<10)+tid] = f2h((float)ds);
            start = end;
        }
    }
    __syncthreads();                                    // B7

    // ---- P7: exclusive f32 scan of 4096 fp16 bucket totals ----
    float f4[4], fsum = 0.f;
    #pragma unroll
    for (int i = 0; i < 4; ++i) { f4[i] = h2f(T[(i<<10)+tid]); fsum += f4[i]; }
    float xf = fsum;
    #pragma unroll
    for (int off = 1; off < 64; off <<= 1) { float y = __shfl_up(xf, off); if (lane >= off) xf += y; }
    if (lane == 63) s_fs[wave] = xf;
    __syncthreads();                                    // B8

    float frun = xf - fsum;
    #pragma unroll
    for (int w = 0; w < NW; ++w) if (w < wave) frun += s_fs[w];
    #pragma unroll
    for (int i = 0; i < 4; ++i) { const float c = f4[i]; T[(i<<10)+tid] = f2h(frun); frun += c; }
    __syncthreads();                                    // B9

    // ---- P9: per kept item: within-bucket inclusive prefix (inline) + log ----
    float logacc = 0.f;
    #pragma unroll
    for (int m = 0; m < 8; ++m) {
        if (kept & (1u << m)) {
            const u32 j = ((m >> 2) << 12) + (tid << 2) + (m & 3);
            const u32 k = vkey[m];
            const int b = (int)(k >> 12);
            const u32 start = b ? A[TP(b - 1)] : 0u;
            const u32 end   = A[TP(b)];
            const u32 ck = ((k & 0xFFFu) << 13) | j;
            double dsm = 0.0;
            for (u32 q = start; q < end; ++q) {
                const u32 k2 = KEY[q];
                if (k2 <= ck) dsm += (double)h2f(EXPH[q]);   // strictly-smaller + own
            }
            const float S = h2f(T[TP(b)]);
            logacc += __logf(S + (float)dsm + EPSF);
        }
    }
    #pragma unroll
    for (int off = 32; off > 0; off >>= 1) logacc += __shfl_down(logacc, off);
    if (lane == 0) s_lg[wave] = logacc;
    __syncthreads();                                    // B10

    if (tid == 0) {
        float lt = 0.f, pt = 0.f;
        #pragma unroll
        for (int w = 0; w < NW; ++w) { lt += s_lg[w]; pt += s_ps[w]; }
        row_out[row] = lt - pt + (float)K * mx;
    }
}

__global__ __launch_bounds__(256) void listmle_finalize(
    const float* __restrict__ row_out, float* __restrict__ out)
{
    __shared__ double red_d[4];
    const int tid = threadIdx.x;
    const int lane = tid & 63, wave = tid >> 6;
    double acc = 0.0;
    for (int r = tid; r < MROWS; r += 256) acc += (double)row_out[r];
    #pragma unroll
    for (int off = 32; off > 0; off >>= 1) acc += __shfl_down(acc, off);
    if (lane == 0) red_d[wave] = acc;
    __syncthreads();
    if (tid == 0) {
        double tot = 0.0;
        for (int w = 0; w < 4; ++w) tot += red_d[w];
        out[0] = (float)(tot / (double)MROWS);
    }
}

extern "C" void kernel_launch(void* const* d_in, const int* in_sizes, int n_in,
                              void* d_out, int out_size, void* d_ws, size_t ws_size,
                              hipStream_t stream) {
    const float* outputs = (const float*)d_in[0];
    const float* runtime = (const float*)d_in[1];
    const int*   idxs    = (const int*)d_in[2];
    float* out = (float*)d_out;
    float* ws  = (float*)d_ws;

    listmle_row_kernel<<<MROWS, BLOCK, 0, stream>>>(outputs, runtime, idxs, ws);
    listmle_finalize<<<1, 256, 0, stream>>>(ws, out);
}